// Round 4
// baseline (413.912 us; speedup 1.0000x reference)
//
#include <hip/hip_runtime.h>

// NLQR: NB=1024, T=128, NS=12, NC=4, N=16.
// Round 9 = Round 8 + register cross-lane data movement (de-LDS the chain):
//  - V rows / vv: ds_bpermute of prev body's vnR/vvR REGISTERS (vns4/vvF
//    buffers deleted — no write, no lgkmcnt interlock on the V chain).
//  - m transpose: 12 ds_bpermute (msh deleted).
//  - Quu + qu: v_readlane broadcasts (lanes 60-63 qt4_, lanes 12-15 qtv_)
//    -> Schur starts ~4cy after MKS instead of after an LDS round trip.
//  - Qux: ds_swizzle imm ((12+c)<<5)|0x10; Qxu row: 4 bpermute from lane
//    48+jc. Issued before Schur so DS latency hides under it. stg4/qtS gone.
//  All routing is bit-identical value movement (lockstep single wave, all
//  lanes active, one BB) — absmax must stay exactly 0.015625.
// Backward-body LDS left: FT staging (3 writes, 3 b128 reads) + uL store.
// R8 result: de-predication -6% (206->194us), VALUBusy 36.5->41.9 — chain
// now dominated by the 4 LDS write->read interlocks this round removes.

#define NBQ 1024
#define TT  128

__device__ __forceinline__ float dotf4(float4 a, float4 b) {
  return a.x*b.x + a.y*b.y + a.z*b.z + a.w*b.w;
}
__device__ __forceinline__ float dpp_qx1(float x) {  // quad_perm [1,0,3,2]
  return __int_as_float(__builtin_amdgcn_mov_dpp(__float_as_int(x), 0xB1, 0xF, 0xF, true));
}
__device__ __forceinline__ float dpp_qx2(float x) {  // quad_perm [2,3,0,1]
  return __int_as_float(__builtin_amdgcn_mov_dpp(__float_as_int(x), 0x4E, 0xF, 0xF, true));
}
template<int Q> __device__ __forceinline__ float4 bcast4(float4 v) {
  // broadcast quad-lane Q's float4 to all lanes of the quad (pure VALU)
  float4 r;
  r.x = __int_as_float(__builtin_amdgcn_mov_dpp(__float_as_int(v.x), Q*0x55, 0xF, 0xF, true));
  r.y = __int_as_float(__builtin_amdgcn_mov_dpp(__float_as_int(v.y), Q*0x55, 0xF, 0xF, true));
  r.z = __int_as_float(__builtin_amdgcn_mov_dpp(__float_as_int(v.z), Q*0x55, 0xF, 0xF, true));
  r.w = __int_as_float(__builtin_amdgcn_mov_dpp(__float_as_int(v.w), Q*0x55, 0xF, 0xF, true));
  return r;
}
__device__ __forceinline__ float bperm(int addr, float v) {  // pull lane[addr>>2].v
  return __int_as_float(__builtin_amdgcn_ds_bpermute(addr, __float_as_int(v)));
}
__device__ __forceinline__ float rdlane(float v, int lane) { // uniform broadcast
  return __int_as_float(__builtin_amdgcn_readlane(__float_as_int(v), lane));
}
template<int IMM> __device__ __forceinline__ float dswz(float v) {
  return __int_as_float(__builtin_amdgcn_ds_swizzle(__float_as_int(v), IMM));
}

#define MKS(K, O, MY)  { float4 mk_ = bcast4<O>(MY);                           \
  qt4_.x += gk_[K]*mk_.x; qt4_.y += gk_[K]*mk_.y;                              \
  qt4_.z += gk_[K]*mk_.z; qt4_.w += gk_[K]*mk_.w; }

// One backward body at time T_. Slot regs QV/PV/CV + F-scalars loaded 4 bodies
// ago; stages F^T for T_-1 from prev slot's F-scalars; reloads self slot with
// T_-4 data. FTC/FTN = compile-time parity buffers. One BB, no LDS value chain.
#define BW_BODY(T_, QV, PV, CV, P0,P1,P2, S0,S1,S2, FTC, FTN)                  \
{                                                                              \
  const int  t_   = (T_);                                                      \
  const long btL_ = b*TT + ((t_ >= 4) ? (t_ - 4) : 0);                         \
  float4 qN_ = *(const float4*)(Qg + btL_*256 + qoff);                         \
  const float* fpL_ = fBase + btL_*fMul + fOfs;                                \
  float fN0_ = fpL_[0], fN1_ = fpL_[fstr_], fN2_ = fpL_[2*fstr_];              \
  float  pN_ = pg[btL_*16 + j];                                                \
  float  cN_ = cug[btL_*4 + q4];                                               \
  /* stage F^T for t_-1: uniform, 3 consecutive elements per lane */           \
  FTN[wix] = P0; FTN[wix+1] = P1; FTN[wix+2] = P2;                             \
  const float4* fj4_ = (const float4*)(FTC + j*12);                            \
  float4 f0_=fj4_[0], f1_=fj4_[1], f2_=fj4_[2];                                \
  /* V rows + vv via bpermute of prev body's registers (no LDS round trip) */  \
  float4 mv0_, mv1_, mv2_, mw_;                                                \
  mv0_.x=bperm(aK0,vnR.x); mv0_.y=bperm(aK0,vnR.y);                            \
  mv0_.z=bperm(aK0,vnR.z); mv0_.w=bperm(aK0,vnR.w);                            \
  mv1_.x=bperm(aK1,vnR.x); mv1_.y=bperm(aK1,vnR.y);                            \
  mv1_.z=bperm(aK1,vnR.z); mv1_.w=bperm(aK1,vnR.w);                            \
  mv2_.x=bperm(aK2,vnR.x); mv2_.y=bperm(aK2,vnR.y);                            \
  mv2_.z=bperm(aK2,vnR.z); mv2_.w=bperm(aK2,vnR.w);                            \
  mw_.x=bperm(am0,vvR); mw_.y=bperm(am1,vvR);                                  \
  mw_.z=bperm(am2,vvR); mw_.w=bperm(am3,vvR);                                  \
  /* m rows via quad broadcast of V rows (single-use -> DPP folds into fma) */ \
  float m0_, m1_, m2_;                                                         \
  { float4 r0_=bcast4<0>(mv0_), r1_=bcast4<0>(mv1_), r2_=bcast4<0>(mv2_);      \
    m0_ = dotf4(r0_,f0_)+dotf4(r1_,f1_)+dotf4(r2_,f2_); }                      \
  { float4 r0_=bcast4<1>(mv0_), r1_=bcast4<1>(mv1_), r2_=bcast4<1>(mv2_);      \
    m1_ = dotf4(r0_,f0_)+dotf4(r1_,f1_)+dotf4(r2_,f2_); }                      \
  { float4 r0_=bcast4<2>(mv0_), r1_=bcast4<2>(mv1_), r2_=bcast4<2>(mv2_);      \
    m2_ = dotf4(r0_,f0_)+dotf4(r1_,f1_)+dotf4(r2_,f2_); }                      \
  /* qtv via vv quad broadcast */                                              \
  float qtv_;                                                                  \
  { float4 w0_=bcast4<0>(mw_), w1_=bcast4<1>(mw_), w2_=bcast4<2>(mw_);         \
    qtv_ = PV + dotf4(w0_,f0_)+dotf4(w1_,f1_)+dotf4(w2_,f2_); }                \
  /* transpose m via bpermute (replaces msh): src lane (q4<<4)+cb4+e */        \
  float4 mys0_, mys1_, mys2_;                                                  \
  mys0_.x=bperm(aT0,m0_); mys0_.y=bperm(aT1,m0_);                              \
  mys0_.z=bperm(aT2,m0_); mys0_.w=bperm(aT3,m0_);                              \
  mys1_.x=bperm(aT0,m1_); mys1_.y=bperm(aT1,m1_);                              \
  mys1_.z=bperm(aT2,m1_); mys1_.w=bperm(aT3,m1_);                              \
  mys2_.x=bperm(aT0,m2_); mys2_.y=bperm(aT1,m2_);                              \
  mys2_.z=bperm(aT2,m2_); mys2_.w=bperm(aT3,m2_);                              \
  /* qt tile: lane (cb, i=l&15) computes Qt[i][4cb..4cb+3] */                  \
  float gk_[12] = {f0_.x,f0_.y,f0_.z,f0_.w, f1_.x,f1_.y,f1_.z,f1_.w,           \
                   f2_.x,f2_.y,f2_.z,f2_.w};                                   \
  float4 qt4_ = QV;                                                            \
  MKS(0,0,mys0_) MKS(1,0,mys1_) MKS(2,0,mys2_)                                 \
  MKS(3,1,mys0_) MKS(4,1,mys1_) MKS(5,1,mys2_)                                 \
  MKS(6,2,mys0_) MKS(7,2,mys1_) MKS(8,2,mys2_)                                 \
  MKS(9,3,mys0_) MKS(10,3,mys1_) MKS(11,3,mys2_)                               \
  /* Qux rows via ds_swizzle (src=(l&0x10)|(12+c) per 32-half), Qxu row via    \
     bpermute lane 48+jc — issued BEFORE Schur so DS latency hides under it */ \
  float4 ux0_, ux1_, ux2_, ux3_, xr_;                                          \
  ux0_.x=dswz<0x190>(qt4_.x); ux0_.y=dswz<0x190>(qt4_.y);                      \
  ux0_.z=dswz<0x190>(qt4_.z); ux0_.w=dswz<0x190>(qt4_.w);                      \
  ux1_.x=dswz<0x1B0>(qt4_.x); ux1_.y=dswz<0x1B0>(qt4_.y);                      \
  ux1_.z=dswz<0x1B0>(qt4_.z); ux1_.w=dswz<0x1B0>(qt4_.w);                      \
  ux2_.x=dswz<0x1D0>(qt4_.x); ux2_.y=dswz<0x1D0>(qt4_.y);                      \
  ux2_.z=dswz<0x1D0>(qt4_.z); ux2_.w=dswz<0x1D0>(qt4_.w);                      \
  ux3_.x=dswz<0x1F0>(qt4_.x); ux3_.y=dswz<0x1F0>(qt4_.y);                      \
  ux3_.z=dswz<0x1F0>(qt4_.z); ux3_.w=dswz<0x1F0>(qt4_.w);                      \
  xr_.x=bperm(aXR,qt4_.x); xr_.y=bperm(aXR,qt4_.y);                            \
  xr_.z=bperm(aXR,qt4_.z); xr_.w=bperm(aXR,qt4_.w);                            \
  /* Quu + qu via readlane (uniform -> SGPR, ~4cy to Schur entry) */           \
  float mm_[16] = {                                                            \
    rdlane(qt4_.x,60), rdlane(qt4_.y,60), rdlane(qt4_.z,60), rdlane(qt4_.w,60),\
    rdlane(qt4_.x,61), rdlane(qt4_.y,61), rdlane(qt4_.z,61), rdlane(qt4_.w,61),\
    rdlane(qt4_.x,62), rdlane(qt4_.y,62), rdlane(qt4_.z,62), rdlane(qt4_.w,62),\
    rdlane(qt4_.x,63), rdlane(qt4_.y,63), rdlane(qt4_.z,63), rdlane(qt4_.w,63)};\
  float4 quv_;                                                                 \
  quv_.x=rdlane(qtv_,12); quv_.y=rdlane(qtv_,13);                              \
  quv_.z=rdlane(qtv_,14); quv_.w=rdlane(qtv_,15);                              \
  /* SPD 2x2-block Schur inverse of Quu (raw v_rcp) */                         \
  float rdp_ = __builtin_amdgcn_rcpf(mm_[0]*mm_[5] - mm_[1]*mm_[1]);           \
  float pi00_ = mm_[5]*rdp_, pi01_ = -mm_[1]*rdp_, pi11_ = mm_[0]*rdp_;        \
  float w00_ = pi00_*mm_[2] + pi01_*mm_[6];                                    \
  float w01_ = pi00_*mm_[3] + pi01_*mm_[7];                                    \
  float w10_ = pi01_*mm_[2] + pi11_*mm_[6];                                    \
  float w11_ = pi01_*mm_[3] + pi11_*mm_[7];                                    \
  float t00_ = mm_[10] - (mm_[2]*w00_ + mm_[6]*w10_);                          \
  float t01_ = mm_[11] - (mm_[2]*w01_ + mm_[6]*w11_);                          \
  float t11_ = mm_[15] - (mm_[3]*w01_ + mm_[7]*w11_);                          \
  float rdt_ = __builtin_amdgcn_rcpf(t00_*t11_ - t01_*t01_);                   \
  float ti00_ = t11_*rdt_, ti01_ = -t01_*rdt_, ti11_ = t00_*rdt_;              \
  float u00_ = -(w00_*ti00_ + w01_*ti01_);                                     \
  float u01_ = -(w00_*ti01_ + w01_*ti11_);                                     \
  float u10_ = -(w10_*ti00_ + w11_*ti01_);                                     \
  float u11_ = -(w10_*ti01_ + w11_*ti11_);                                     \
  float i00_ = pi00_ - (u00_*w00_ + u01_*w01_);                                \
  float i01_ = pi01_ - (u00_*w10_ + u01_*w11_);                                \
  float i11_ = pi11_ - (u10_*w10_ + u11_*w11_);                                \
  float inv_[16] = { i00_, i01_, u00_, u01_,                                   \
                     i01_, i11_, u10_, u11_,                                   \
                     u00_, u10_, ti00_, ti01_,                                 \
                     u01_, u11_, ti01_, ti11_ };                               \
  float kt0_ = -(inv_[0] *quv_.x + inv_[1] *quv_.y + inv_[2] *quv_.z + inv_[3] *quv_.w); \
  float kt1_ = -(inv_[4] *quv_.x + inv_[5] *quv_.y + inv_[6] *quv_.z + inv_[7] *quv_.w); \
  float kt2_ = -(inv_[8] *quv_.x + inv_[9] *quv_.y + inv_[10]*quv_.z + inv_[11]*quv_.w); \
  float kt3_ = -(inv_[12]*quv_.x + inv_[13]*quv_.y + inv_[14]*quv_.z + inv_[15]*quv_.w); \
  float4 kc_[4];                                                               \
  _Pragma("unroll")                                                            \
  for (int c_ = 0; c_ < 4; ++c_) {                                             \
    kc_[c_].x = -(inv_[c_*4+0]*ux0_.x + inv_[c_*4+1]*ux1_.x + inv_[c_*4+2]*ux2_.x + inv_[c_*4+3]*ux3_.x); \
    kc_[c_].y = -(inv_[c_*4+0]*ux0_.y + inv_[c_*4+1]*ux1_.y + inv_[c_*4+2]*ux2_.y + inv_[c_*4+3]*ux3_.y); \
    kc_[c_].z = -(inv_[c_*4+0]*ux0_.z + inv_[c_*4+1]*ux1_.z + inv_[c_*4+2]*ux2_.z + inv_[c_*4+3]*ux3_.z); \
    kc_[c_].w = -(inv_[c_*4+0]*ux0_.w + inv_[c_*4+1]*ux1_.w + inv_[c_*4+2]*ux2_.w + inv_[c_*4+3]*ux3_.w); \
  }                                                                            \
  /* vn/vv stay in REGISTERS for next body's bpermute gather */                \
  float4 vn4_;                                                                 \
  vn4_.x = qt4_.x + xr_.x*kc_[0].x + xr_.y*kc_[1].x + xr_.z*kc_[2].x + xr_.w*kc_[3].x; \
  vn4_.y = qt4_.y + xr_.x*kc_[0].y + xr_.y*kc_[1].y + xr_.z*kc_[2].y + xr_.w*kc_[3].y; \
  vn4_.z = qt4_.z + xr_.x*kc_[0].z + xr_.y*kc_[1].z + xr_.z*kc_[2].z + xr_.w*kc_[3].z; \
  vn4_.w = qt4_.w + xr_.x*kc_[0].w + xr_.y*kc_[1].w + xr_.z*kc_[2].w + xr_.w*kc_[3].w; \
  vnR = vn4_;                                                                  \
  vvR = qtv_ + xr_.x*kt0_ + xr_.y*kt1_ + xr_.z*kt2_ + xr_.w*kt3_;              \
  float uv_ = CV + ((q4==0)?kt0_:(q4==1)?kt1_:(q4==2)?kt2_:kt3_);              \
  upt[0] = uv_; upt -= ustp;                                                   \
  QV = qN_; S0 = fN0_; S1 = fN1_; S2 = fN2_; PV = pN_; CV = cN_;               \
}

__global__ __launch_bounds__(64, 1) void lqr_fused(
    const float* __restrict__ Qg, const float* __restrict__ pg,
    const float* __restrict__ Ag, const float* __restrict__ Bg,
    const float* __restrict__ cug, const float* __restrict__ xinit,
    float* __restrict__ out)
{
  __shared__ __align__(16) float lds[2496];
  float*  FT0  = lds;          // [16][12] F^T buffer 0
  float*  FT1  = lds + 192;    // [16][12] F^T buffer 1
  float*  uL   = lds + 384;    // [128][4]
  float*  dmpS = lds + 896;    // [64] dump row (never read)
  float*  xsL  = lds + 960;    // [128][12]

  const int l    = threadIdx.x;
  const int j    = l & 15;         // m-step col / qt-step row i
  const int r    = l >> 4;         // m-step row group
  const int q4   = l & 3;
  const int cb   = l >> 4;         // qt-step column block
  const int cb4  = cb << 2;
  const int dmin = (q4 < 2) ? q4 : 2;
  const int jc   = (j < 12) ? j : 11;
  const long b   = blockIdx.x;
  const int  kR  = 3*r + dmin;

  // cross-lane address registers (byte = lane*4)
  const int aK0 = kR << 2, aK1 = (16 + kR) << 2, aK2 = (32 + kR) << 2;
  const int am0 = (4*dmin) << 2,     am1 = (4*dmin + 1) << 2;
  const int am2 = (4*dmin + 2) << 2, am3 = (4*dmin + 3) << 2;
  const int aT0 = ((q4<<4) + cb4 + 0) << 2, aT1 = ((q4<<4) + cb4 + 1) << 2;
  const int aT2 = ((q4<<4) + cb4 + 2) << 2, aT3 = ((q4<<4) + cb4 + 3) << 2;
  const int aXR = (48 + jc) << 2;

  // uniform F^T staging map: lane l stages FT[n][k0..k0+2]
  const int  n_   = l >> 2;
  const int  k0_  = 3*(l & 3);
  const int  wix  = n_*12 + k0_;
  const bool isA  = (n_ < 12);
  const float* fBase = isA ? Ag : Bg;
  const int  fMul  = isA ? 144 : 48;
  const int  fstr_ = isA ? 12  : 4;
  const int  fOfs  = isA ? (k0_*12 + n_) : (k0_*4 + (n_ - 12));
  const int  qoff  = j * 16 + cb4;

  // u store: lanes 0..3 write uL[t*4+l], others to dump (b32, conflict-free)
  float* up0 = (l < 4) ? (uL + l) : (dmpS + l);
  const int ustp = (l < 4) ? 4 : 0;
  float* upt = up0 + 127*ustp;   // walks t = 127..0 via upt -= ustp

  float* xs_out = out;
  float* us_out = out + (long)NBQ*TT*12;
  float* c_out  = out + (long)NBQ*TT*12 + (long)NBQ*TT*4;

  // V carry lives in registers now (V0 = 0)
  float4 vnR = make_float4(0.f, 0.f, 0.f, 0.f);
  float  vvR = 0.f;

  // ---- prologue: 4 slots (t = 127..124), stage FT(127) into buf1 ----
  const long base = b*TT;
  float4 q3v,q2v,q1v,q0v;
  float  p3v,c3v,p2v,c2v,p1v,c1v,p0v,c0v;
  float  f3a,f3b,f3c, f2a,f2b,f2c, f1a,f1b,f1c, f0a,f0b,f0c;
  {
    long bt;
    bt = base+127; q3v=*(const float4*)(Qg+bt*256+qoff); p3v=pg[bt*16+j]; c3v=cug[bt*4+q4];
    { const float* fp = fBase + bt*fMul + fOfs; f3a=fp[0]; f3b=fp[fstr_]; f3c=fp[2*fstr_]; }
    bt = base+126; q2v=*(const float4*)(Qg+bt*256+qoff); p2v=pg[bt*16+j]; c2v=cug[bt*4+q4];
    { const float* fp = fBase + bt*fMul + fOfs; f2a=fp[0]; f2b=fp[fstr_]; f2c=fp[2*fstr_]; }
    bt = base+125; q1v=*(const float4*)(Qg+bt*256+qoff); p1v=pg[bt*16+j]; c1v=cug[bt*4+q4];
    { const float* fp = fBase + bt*fMul + fOfs; f1a=fp[0]; f1b=fp[fstr_]; f1c=fp[2*fstr_]; }
    bt = base+124; q0v=*(const float4*)(Qg+bt*256+qoff); p0v=pg[bt*16+j]; c0v=cug[bt*4+q4];
    { const float* fp = fBase + bt*fMul + fOfs; f0a=fp[0]; f0b=fp[fstr_]; f0c=fp[2*fstr_]; }
  }
  FT1[wix] = f3a; FT1[wix+1] = f3b; FT1[wix+2] = f3c;

  // ---- backward scan, unrolled x4 with slot rotation ----
  #pragma unroll 1
  for (int tb = TT-1; tb >= 3; tb -= 4) {
    BW_BODY(tb,   q3v, p3v, c3v,  f2a,f2b,f2c,  f3a,f3b,f3c, FT1, FT0)
    BW_BODY(tb-1, q2v, p2v, c2v,  f1a,f1b,f1c,  f2a,f2b,f2c, FT0, FT1)
    BW_BODY(tb-2, q1v, p1v, c1v,  f0a,f0b,f0c,  f1a,f1b,f1c, FT1, FT0)
    BW_BODY(tb-3, q0v, p0v, c0v,  f3a,f3b,f3c,  f0a,f0b,f0c, FT0, FT1)
  }

  // ---- coalesced us flush ----
  #pragma unroll
  for (int i_ = 0; i_ < 8; ++i_) us_out[b*512 + i_*64 + l] = uL[i_*64 + l];

  // ---------------- forward rollout + cost ----------------
  const int i4  = l >> 2;
  const int c0f = q4 << 2;
  const int i4c = (i4 < 12) ? i4 : 11;
  const int sl0 = (c0f+0)<<2, sl1 = (c0f+1)<<2, sl2 = (c0f+2)<<2, sl3 = (c0f+3)<<2;
  float s = xinit[b*12 + i4c];
  float cacc = 0.f;

  // de-predicated x store + cost mask
  const bool xc_ = (q4 == 0) && (i4 < 12);
  float* xpt = xc_ ? (xsL + i4) : (dmpS + l);
  const int xstp = xc_ ? 12 : 0;
  const float q0m = (q4 == 0) ? 1.0f : 0.0f;

  const long bt0 = base;
  float4 qfA = *(const float4*)(Qg + bt0*256 + 4*l);
  float4 ffA = (q4 < 3) ? *(const float4*)(Ag + bt0*144 + i4c*12 + c0f)
                        : *(const float4*)(Bg + bt0*48  + i4c*4);
  float  pfA = pg[bt0*16 + i4];
  float4 qfB = *(const float4*)(Qg + (bt0+1)*256 + 4*l);
  float4 ffB = (q4 < 3) ? *(const float4*)(Ag + (bt0+1)*144 + i4c*12 + c0f)
                        : *(const float4*)(Bg + (bt0+1)*48  + i4c*4);
  float  pfB = pg[(bt0+1)*16 + i4];
  float4 qfC = *(const float4*)(Qg + (bt0+2)*256 + 4*l);
  float4 ffC = (q4 < 3) ? *(const float4*)(Ag + (bt0+2)*144 + i4c*12 + c0f)
                        : *(const float4*)(Bg + (bt0+2)*48  + i4c*4);
  float  pfC = pg[(bt0+2)*16 + i4];

  #pragma unroll 1
  for (int t = 0; t < TT; ++t) {
    const long btp = bt0 + ((t+3 < TT-1) ? t+3 : TT-1);
    float4 qfD = *(const float4*)(Qg + btp*256 + 4*l);
    float4 ffD = (q4 < 3) ? *(const float4*)(Ag + btp*144 + i4c*12 + c0f)
                          : *(const float4*)(Bg + btp*48  + i4c*4);
    float  pfD = pg[btp*16 + i4];

    float4 u4 = *(const float4*)(uL + t*4);

    float4 xg;
    xg.x = __shfl(s, sl0, 64); xg.y = __shfl(s, sl1, 64);
    xg.z = __shfl(s, sl2, 64); xg.w = __shfl(s, sl3, 64);
    float4 xuq = (q4 < 3) ? xg : u4;
    float xui = (i4 < 12) ? s
              : (i4 == 12) ? u4.x : (i4 == 13) ? u4.y : (i4 == 14) ? u4.z : u4.w;

    xpt[0] = s; xpt += xstp;

    cacc += 0.5f * xui * dotf4(qfA, xuq);
    cacc += q0m * (xui * pfA);

    float zx = dotf4(ffA, xuq);
    zx += dpp_qx1(zx);
    zx += dpp_qx2(zx);
    s = zx;

    qfA = qfB; ffA = ffB; pfA = pfB;
    qfB = qfC; ffB = ffC; pfB = pfC;
    qfC = qfD; ffC = ffD; pfC = pfD;
  }

  // ---- coalesced xs flush ----
  #pragma unroll
  for (int i_ = 0; i_ < 24; ++i_) xs_out[b*1536 + i_*64 + l] = xsL[i_*64 + l];

  cacc += __shfl_xor(cacc, 32, 64);
  cacc += __shfl_xor(cacc, 16, 64);
  cacc += __shfl_xor(cacc, 8, 64);
  cacc += __shfl_xor(cacc, 4, 64);
  cacc += dpp_qx2(cacc);
  cacc += dpp_qx1(cacc);
  if (l == 0) c_out[b] = cacc;
}

extern "C" void kernel_launch(void* const* d_in, const int* in_sizes, int n_in,
                              void* d_out, int out_size, void* d_ws, size_t ws_size,
                              hipStream_t stream) {
  const float* xinit = (const float*)d_in[0];
  // d_in[1] = current_x (unused by reference), d_in[7] = time (unused)
  const float* cu = (const float*)d_in[2];
  const float* Q  = (const float*)d_in[3];
  const float* p  = (const float*)d_in[4];
  const float* A  = (const float*)d_in[5];
  const float* Bm = (const float*)d_in[6];
  float* out = (float*)d_out;

  lqr_fused<<<dim3(NBQ), dim3(64), 0, stream>>>(Q, p, A, Bm, cu, xinit, out);
}

// Round 5
// 352.466 us; speedup vs baseline: 1.1743x; 1.1743x over previous
//
#include <hip/hip_runtime.h>

// NLQR: NB=1024, T=128, NS=12, NC=4, N=16.
// Round 10 = Round 8 (best: 194us rocprof) + readlane-only piece of R9:
//  - Quu (mm_) via v_readlane of lanes 60-63's qt4_ registers; qu (quv_) via
//    v_readlane of lanes 12-15's qtv_. readlane is VALU (no DS pipe, no
//    lgkmcnt) -> Schur starts ~4cy after MKS instead of after the stg4
//    write->read interlock. qtS buffer deleted (DS ops ~31 -> ~25/body).
//  - stg4 write + ux/xr reads (only needed post-inv_) now issue on the DS
//    pipe IN PARALLEL with the ~200cy Schur chain.
// R9 lesson (194->239us, conflicts 2.47M->4.57M): bpermute/ds_swizzle ARE
// DS-pipe ops with crossbar conflicts — swapping LDS write/read for a
// bpermute swarm RAISED DS-op count 31->55. Reverted; only readlane kept.
// R8 design retained: single-BB bodies (de-predication), all-lane publish
// buffers stg4/vns4/vvF, uniform FT staging, coalesced us/xs flush,
// 4-deep global prefetch, zero barriers, 1 wave/block.

#define NBQ 1024
#define TT  128

// publish-slot swizzle: distinct bank quads for broadcast reads
#define SSLOT(x) ((x) ^ ((((x) >> 4) << 1)))

__device__ __forceinline__ float dotf4(float4 a, float4 b) {
  return a.x*b.x + a.y*b.y + a.z*b.z + a.w*b.w;
}
__device__ __forceinline__ float dpp_qx1(float x) {  // quad_perm [1,0,3,2]
  return __int_as_float(__builtin_amdgcn_mov_dpp(__float_as_int(x), 0xB1, 0xF, 0xF, true));
}
__device__ __forceinline__ float dpp_qx2(float x) {  // quad_perm [2,3,0,1]
  return __int_as_float(__builtin_amdgcn_mov_dpp(__float_as_int(x), 0x4E, 0xF, 0xF, true));
}
template<int Q> __device__ __forceinline__ float4 bcast4(float4 v) {
  // broadcast quad-lane Q's float4 to all lanes of the quad (pure VALU)
  float4 r;
  r.x = __int_as_float(__builtin_amdgcn_mov_dpp(__float_as_int(v.x), Q*0x55, 0xF, 0xF, true));
  r.y = __int_as_float(__builtin_amdgcn_mov_dpp(__float_as_int(v.y), Q*0x55, 0xF, 0xF, true));
  r.z = __int_as_float(__builtin_amdgcn_mov_dpp(__float_as_int(v.z), Q*0x55, 0xF, 0xF, true));
  r.w = __int_as_float(__builtin_amdgcn_mov_dpp(__float_as_int(v.w), Q*0x55, 0xF, 0xF, true));
  return r;
}
__device__ __forceinline__ float rdlane(float v, int lane) { // uniform broadcast (VALU, no DS)
  return __int_as_float(__builtin_amdgcn_readlane(__float_as_int(v), lane));
}

#define MKS(K, O, MY)  { float4 mk_ = bcast4<O>(MY);                           \
  qt4_.x += gk_[K]*mk_.x; qt4_.y += gk_[K]*mk_.y;                              \
  qt4_.z += gk_[K]*mk_.z; qt4_.w += gk_[K]*mk_.w; }

// One backward body at time T_. Slot regs QV/PV/CV + F-scalars loaded 4 bodies
// ago; stages F^T for T_-1 from prev slot's F-scalars; reloads self slot with
// T_-4 data. FTC/FTN = compile-time parity buffers. ZERO exec-mask regions.
#define BW_BODY(T_, QV, PV, CV, P0,P1,P2, S0,S1,S2, FTC, FTN)                  \
{                                                                              \
  const int  t_   = (T_);                                                      \
  const long btL_ = b*TT + ((t_ >= 4) ? (t_ - 4) : 0);                         \
  float4 qN_ = *(const float4*)(Qg + btL_*256 + qoff);                         \
  const float* fpL_ = fBase + btL_*fMul + fOfs;                                \
  float fN0_ = fpL_[0], fN1_ = fpL_[fstr_], fN2_ = fpL_[2*fstr_];              \
  float  pN_ = pg[btL_*16 + j];                                                \
  float  cN_ = cug[btL_*4 + q4];                                               \
  /* stage F^T for t_-1: uniform, 3 consecutive elements per lane */           \
  FTN[wix] = P0; FTN[wix+1] = P1; FTN[wix+2] = P2;                             \
  /* reads: f = F col (l&15), own V row piece from publish slots, vv */        \
  const float4* fj4_ = (const float4*)(FTC + j*12);                            \
  float4 f0_=fj4_[0], f1_=fj4_[1], f2_=fj4_[2];                                \
  float4 mv0_ = vns4[kR], mv1_ = vns4[16+kR], mv2_ = vns4[32+kR];              \
  float4 mw_ = *(const float4*)(vvF + 4*dmin);                                 \
  /* m rows via quad broadcast of V rows (single-use -> DPP folds into fma) */ \
  float m0_, m1_, m2_;                                                         \
  { float4 r0_=bcast4<0>(mv0_), r1_=bcast4<0>(mv1_), r2_=bcast4<0>(mv2_);      \
    m0_ = dotf4(r0_,f0_)+dotf4(r1_,f1_)+dotf4(r2_,f2_); }                      \
  { float4 r0_=bcast4<1>(mv0_), r1_=bcast4<1>(mv1_), r2_=bcast4<1>(mv2_);      \
    m1_ = dotf4(r0_,f0_)+dotf4(r1_,f1_)+dotf4(r2_,f2_); }                      \
  { float4 r0_=bcast4<2>(mv0_), r1_=bcast4<2>(mv1_), r2_=bcast4<2>(mv2_);      \
    m2_ = dotf4(r0_,f0_)+dotf4(r1_,f1_)+dotf4(r2_,f2_); }                      \
  msh[(3*r+0)*16 + j] = m0_;                                                   \
  msh[(3*r+1)*16 + j] = m1_;                                                   \
  msh[(3*r+2)*16 + j] = m2_;                                                   \
  /* qtv via vv quad broadcast (fills msh write->read latency) */              \
  float qtv_;                                                                  \
  { float4 w0_=bcast4<0>(mw_), w1_=bcast4<1>(mw_), w2_=bcast4<2>(mw_);         \
    qtv_ = PV + dotf4(w0_,f0_)+dotf4(w1_,f1_)+dotf4(w2_,f2_); }                \
  /* qt tile: lane (cb, i=l&15) computes Qt[i][4cb..4cb+3] */                  \
  float gk_[12] = {f0_.x,f0_.y,f0_.z,f0_.w, f1_.x,f1_.y,f1_.z,f1_.w,           \
                   f2_.x,f2_.y,f2_.z,f2_.w};                                   \
  float4 mys0_ = *(const float4*)(msh + (3*q4+0)*16 + cb4);                    \
  float4 mys1_ = *(const float4*)(msh + (3*q4+1)*16 + cb4);                    \
  float4 mys2_ = *(const float4*)(msh + (3*q4+2)*16 + cb4);                    \
  float4 qt4_ = QV;                                                            \
  MKS(0,0,mys0_) MKS(1,0,mys1_) MKS(2,0,mys2_)                                 \
  MKS(3,1,mys0_) MKS(4,1,mys1_) MKS(5,1,mys2_)                                 \
  MKS(6,2,mys0_) MKS(7,2,mys1_) MKS(8,2,mys2_)                                 \
  MKS(9,3,mys0_) MKS(10,3,mys1_) MKS(11,3,mys2_)                               \
  /* publish qt4_ (needed for ux/xr gather); DS write overlaps Schur below */  \
  stg4[sw_] = qt4_;                                                            \
  /* ux/xr reads issue on DS pipe; results consumed only after inv_ ready */   \
  float4 ux0_ = stg4[sux0], ux1_ = stg4[sux1], ux2_ = stg4[sux2], ux3_ = stg4[sux3]; \
  float4 xr_  = stg4[sxr];                                                     \
  /* Quu + qu via readlane (VALU, no DS): Schur entry ~4cy after MKS */        \
  float mm_[16] = {                                                            \
    rdlane(qt4_.x,60), rdlane(qt4_.y,60), rdlane(qt4_.z,60), rdlane(qt4_.w,60),\
    rdlane(qt4_.x,61), rdlane(qt4_.y,61), rdlane(qt4_.z,61), rdlane(qt4_.w,61),\
    rdlane(qt4_.x,62), rdlane(qt4_.y,62), rdlane(qt4_.z,62), rdlane(qt4_.w,62),\
    rdlane(qt4_.x,63), rdlane(qt4_.y,63), rdlane(qt4_.z,63), rdlane(qt4_.w,63)};\
  float4 quv_;                                                                 \
  quv_.x=rdlane(qtv_,12); quv_.y=rdlane(qtv_,13);                              \
  quv_.z=rdlane(qtv_,14); quv_.w=rdlane(qtv_,15);                              \
  /* SPD 2x2-block Schur inverse of Quu (raw v_rcp) */                         \
  float rdp_ = __builtin_amdgcn_rcpf(mm_[0]*mm_[5] - mm_[1]*mm_[1]);           \
  float pi00_ = mm_[5]*rdp_, pi01_ = -mm_[1]*rdp_, pi11_ = mm_[0]*rdp_;        \
  float w00_ = pi00_*mm_[2] + pi01_*mm_[6];                                    \
  float w01_ = pi00_*mm_[3] + pi01_*mm_[7];                                    \
  float w10_ = pi01_*mm_[2] + pi11_*mm_[6];                                    \
  float w11_ = pi01_*mm_[3] + pi11_*mm_[7];                                    \
  float t00_ = mm_[10] - (mm_[2]*w00_ + mm_[6]*w10_);                          \
  float t01_ = mm_[11] - (mm_[2]*w01_ + mm_[6]*w11_);                          \
  float t11_ = mm_[15] - (mm_[3]*w01_ + mm_[7]*w11_);                          \
  float rdt_ = __builtin_amdgcn_rcpf(t00_*t11_ - t01_*t01_);                   \
  float ti00_ = t11_*rdt_, ti01_ = -t01_*rdt_, ti11_ = t00_*rdt_;              \
  float u00_ = -(w00_*ti00_ + w01_*ti01_);                                     \
  float u01_ = -(w00_*ti01_ + w01_*ti11_);                                     \
  float u10_ = -(w10_*ti00_ + w11_*ti01_);                                     \
  float u11_ = -(w10_*ti01_ + w11_*ti11_);                                     \
  float i00_ = pi00_ - (u00_*w00_ + u01_*w01_);                                \
  float i01_ = pi01_ - (u00_*w10_ + u01_*w11_);                                \
  float i11_ = pi11_ - (u10_*w10_ + u11_*w11_);                                \
  float inv_[16] = { i00_, i01_, u00_, u01_,                                   \
                     i01_, i11_, u10_, u11_,                                   \
                     u00_, u10_, ti00_, ti01_,                                 \
                     u01_, u11_, ti01_, ti11_ };                               \
  float kt0_ = -(inv_[0] *quv_.x + inv_[1] *quv_.y + inv_[2] *quv_.z + inv_[3] *quv_.w); \
  float kt1_ = -(inv_[4] *quv_.x + inv_[5] *quv_.y + inv_[6] *quv_.z + inv_[7] *quv_.w); \
  float kt2_ = -(inv_[8] *quv_.x + inv_[9] *quv_.y + inv_[10]*quv_.z + inv_[11]*quv_.w); \
  float kt3_ = -(inv_[12]*quv_.x + inv_[13]*quv_.y + inv_[14]*quv_.z + inv_[15]*quv_.w); \
  float4 kc_[4];                                                               \
  _Pragma("unroll")                                                            \
  for (int c_ = 0; c_ < 4; ++c_) {                                             \
    kc_[c_].x = -(inv_[c_*4+0]*ux0_.x + inv_[c_*4+1]*ux1_.x + inv_[c_*4+2]*ux2_.x + inv_[c_*4+3]*ux3_.x); \
    kc_[c_].y = -(inv_[c_*4+0]*ux0_.y + inv_[c_*4+1]*ux1_.y + inv_[c_*4+2]*ux2_.y + inv_[c_*4+3]*ux3_.y); \
    kc_[c_].z = -(inv_[c_*4+0]*ux0_.z + inv_[c_*4+1]*ux1_.z + inv_[c_*4+2]*ux2_.z + inv_[c_*4+3]*ux3_.z); \
    kc_[c_].w = -(inv_[c_*4+0]*ux0_.w + inv_[c_*4+1]*ux1_.w + inv_[c_*4+2]*ux2_.w + inv_[c_*4+3]*ux3_.w); \
  }                                                                            \
  /* all-lane vn publish (garbage slots never read) */                         \
  float4 vn4_;                                                                 \
  vn4_.x = qt4_.x + xr_.x*kc_[0].x + xr_.y*kc_[1].x + xr_.z*kc_[2].x + xr_.w*kc_[3].x; \
  vn4_.y = qt4_.y + xr_.x*kc_[0].y + xr_.y*kc_[1].y + xr_.z*kc_[2].y + xr_.w*kc_[3].y; \
  vn4_.z = qt4_.z + xr_.x*kc_[0].z + xr_.y*kc_[1].z + xr_.z*kc_[2].z + xr_.w*kc_[3].z; \
  vn4_.w = qt4_.w + xr_.x*kc_[0].w + xr_.y*kc_[1].w + xr_.z*kc_[2].w + xr_.w*kc_[3].w; \
  vns4[l] = vn4_;                                                              \
  vvF[l] = qtv_ + xr_.x*kt0_ + xr_.y*kt1_ + xr_.z*kt2_ + xr_.w*kt3_;           \
  float uv_ = CV + ((q4==0)?kt0_:(q4==1)?kt1_:(q4==2)?kt2_:kt3_);              \
  upt[0] = uv_; upt -= ustp;                                                   \
  QV = qN_; S0 = fN0_; S1 = fN1_; S2 = fN2_; PV = pN_; CV = cN_;               \
}

__global__ __launch_bounds__(64, 1) void lqr_fused(
    const float* __restrict__ Qg, const float* __restrict__ pg,
    const float* __restrict__ Ag, const float* __restrict__ Bg,
    const float* __restrict__ cug, const float* __restrict__ xinit,
    float* __restrict__ out)
{
  __shared__ __align__(16) float lds[3264];
  float*  FT0  = lds;                    // [16][12] F^T buffer 0
  float*  FT1  = lds + 192;              // [16][12] F^T buffer 1
  float*  msh  = lds + 384;              // [12][16]
  float4* stg4 = (float4*)(lds + 576);   // [64] qt4_ publish (swizzled slots)
  float4* vns4 = (float4*)(lds + 832);   // [64] vn4_ publish
  float*  vvF  = lds + 1088;             // [64] vv publish
  float*  uL   = lds + 1152;             // [128][4]
  float*  dmpS = lds + 1664;             // [64] dump row (never read)
  float*  xsL  = lds + 1728;             // [128][12]

  const int l    = threadIdx.x;
  const int j    = l & 15;         // m-step col / qt-step row i
  const int r    = l >> 4;         // m-step row group
  const int q4   = l & 3;
  const int cb   = l >> 4;         // qt-step column block
  const int cb4  = cb << 2;
  const int dmin = (q4 < 2) ? q4 : 2;
  const int jc   = (j < 12) ? j : 11;
  const long b   = blockIdx.x;
  const int  kR  = 3*r + dmin;

  // publish-slot indices (hoisted)
  const int sw_  = SSLOT(l);
  const int sux0 = SSLOT(16*cb + 12), sux1 = SSLOT(16*cb + 13);
  const int sux2 = SSLOT(16*cb + 14), sux3 = SSLOT(16*cb + 15);
  const int sxr  = SSLOT(48 + jc);

  // uniform F^T staging map: lane l stages FT[n][k0..k0+2]
  const int  n_   = l >> 2;
  const int  k0_  = 3*(l & 3);
  const int  wix  = n_*12 + k0_;
  const bool isA  = (n_ < 12);
  const float* fBase = isA ? Ag : Bg;
  const int  fMul  = isA ? 144 : 48;
  const int  fstr_ = isA ? 12  : 4;
  const int  fOfs  = isA ? (k0_*12 + n_) : (k0_*4 + (n_ - 12));
  const int  qoff  = j * 16 + cb4;

  // u store: lanes 0..3 write uL[t*4+l], others to dump (b32, conflict-free)
  float* up0 = (l < 4) ? (uL + l) : (dmpS + l);
  const int ustp = (l < 4) ? 4 : 0;
  float* upt = up0 + 127*ustp;   // walks t = 127..0 via upt -= ustp

  float* xs_out = out;
  float* us_out = out + (long)NBQ*TT*12;
  float* c_out  = out + (long)NBQ*TT*12 + (long)NBQ*TT*4;

  vns4[l] = make_float4(0.f,0.f,0.f,0.f);
  vvF[l]  = 0.f;

  // ---- prologue: 4 slots (t = 127..124), stage FT(127) into buf1 ----
  const long base = b*TT;
  float4 q3v,q2v,q1v,q0v;
  float  p3v,c3v,p2v,c2v,p1v,c1v,p0v,c0v;
  float  f3a,f3b,f3c, f2a,f2b,f2c, f1a,f1b,f1c, f0a,f0b,f0c;
  {
    long bt;
    bt = base+127; q3v=*(const float4*)(Qg+bt*256+qoff); p3v=pg[bt*16+j]; c3v=cug[bt*4+q4];
    { const float* fp = fBase + bt*fMul + fOfs; f3a=fp[0]; f3b=fp[fstr_]; f3c=fp[2*fstr_]; }
    bt = base+126; q2v=*(const float4*)(Qg+bt*256+qoff); p2v=pg[bt*16+j]; c2v=cug[bt*4+q4];
    { const float* fp = fBase + bt*fMul + fOfs; f2a=fp[0]; f2b=fp[fstr_]; f2c=fp[2*fstr_]; }
    bt = base+125; q1v=*(const float4*)(Qg+bt*256+qoff); p1v=pg[bt*16+j]; c1v=cug[bt*4+q4];
    { const float* fp = fBase + bt*fMul + fOfs; f1a=fp[0]; f1b=fp[fstr_]; f1c=fp[2*fstr_]; }
    bt = base+124; q0v=*(const float4*)(Qg+bt*256+qoff); p0v=pg[bt*16+j]; c0v=cug[bt*4+q4];
    { const float* fp = fBase + bt*fMul + fOfs; f0a=fp[0]; f0b=fp[fstr_]; f0c=fp[2*fstr_]; }
  }
  FT1[wix] = f3a; FT1[wix+1] = f3b; FT1[wix+2] = f3c;

  // ---- backward scan, unrolled x4 with slot rotation ----
  #pragma unroll 1
  for (int tb = TT-1; tb >= 3; tb -= 4) {
    BW_BODY(tb,   q3v, p3v, c3v,  f2a,f2b,f2c,  f3a,f3b,f3c, FT1, FT0)
    BW_BODY(tb-1, q2v, p2v, c2v,  f1a,f1b,f1c,  f2a,f2b,f2c, FT0, FT1)
    BW_BODY(tb-2, q1v, p1v, c1v,  f0a,f0b,f0c,  f1a,f1b,f1c, FT1, FT0)
    BW_BODY(tb-3, q0v, p0v, c0v,  f3a,f3b,f3c,  f0a,f0b,f0c, FT0, FT1)
  }

  // ---- coalesced us flush (replaces per-body predicated global store) ----
  #pragma unroll
  for (int i_ = 0; i_ < 8; ++i_) us_out[b*512 + i_*64 + l] = uL[i_*64 + l];

  // ---------------- forward rollout + cost ----------------
  const int i4  = l >> 2;
  const int c0f = q4 << 2;
  const int i4c = (i4 < 12) ? i4 : 11;
  const int sl0 = (c0f+0)<<2, sl1 = (c0f+1)<<2, sl2 = (c0f+2)<<2, sl3 = (c0f+3)<<2;
  float s = xinit[b*12 + i4c];
  float cacc = 0.f;

  // de-predicated x store + cost mask
  const bool xc_ = (q4 == 0) && (i4 < 12);
  float* xpt = xc_ ? (xsL + i4) : (dmpS + l);
  const int xstp = xc_ ? 12 : 0;
  const float q0m = (q4 == 0) ? 1.0f : 0.0f;

  const long bt0 = base;
  float4 qfA = *(const float4*)(Qg + bt0*256 + 4*l);
  float4 ffA = (q4 < 3) ? *(const float4*)(Ag + bt0*144 + i4c*12 + c0f)
                        : *(const float4*)(Bg + bt0*48  + i4c*4);
  float  pfA = pg[bt0*16 + i4];
  float4 qfB = *(const float4*)(Qg + (bt0+1)*256 + 4*l);
  float4 ffB = (q4 < 3) ? *(const float4*)(Ag + (bt0+1)*144 + i4c*12 + c0f)
                        : *(const float4*)(Bg + (bt0+1)*48  + i4c*4);
  float  pfB = pg[(bt0+1)*16 + i4];
  float4 qfC = *(const float4*)(Qg + (bt0+2)*256 + 4*l);
  float4 ffC = (q4 < 3) ? *(const float4*)(Ag + (bt0+2)*144 + i4c*12 + c0f)
                        : *(const float4*)(Bg + (bt0+2)*48  + i4c*4);
  float  pfC = pg[(bt0+2)*16 + i4];

  #pragma unroll 1
  for (int t = 0; t < TT; ++t) {
    const long btp = bt0 + ((t+3 < TT-1) ? t+3 : TT-1);
    float4 qfD = *(const float4*)(Qg + btp*256 + 4*l);
    float4 ffD = (q4 < 3) ? *(const float4*)(Ag + btp*144 + i4c*12 + c0f)
                          : *(const float4*)(Bg + btp*48  + i4c*4);
    float  pfD = pg[btp*16 + i4];

    float4 u4 = *(const float4*)(uL + t*4);

    float4 xg;
    xg.x = __shfl(s, sl0, 64); xg.y = __shfl(s, sl1, 64);
    xg.z = __shfl(s, sl2, 64); xg.w = __shfl(s, sl3, 64);
    float4 xuq = (q4 < 3) ? xg : u4;
    float xui = (i4 < 12) ? s
              : (i4 == 12) ? u4.x : (i4 == 13) ? u4.y : (i4 == 14) ? u4.z : u4.w;

    xpt[0] = s; xpt += xstp;

    cacc += 0.5f * xui * dotf4(qfA, xuq);
    cacc += q0m * (xui * pfA);

    float zx = dotf4(ffA, xuq);
    zx += dpp_qx1(zx);
    zx += dpp_qx2(zx);
    s = zx;

    qfA = qfB; ffA = ffB; pfA = pfB;
    qfB = qfC; ffB = ffC; pfB = pfC;
    qfC = qfD; ffC = ffD; pfC = pfD;
  }

  // ---- coalesced xs flush ----
  #pragma unroll
  for (int i_ = 0; i_ < 24; ++i_) xs_out[b*1536 + i_*64 + l] = xsL[i_*64 + l];

  cacc += __shfl_xor(cacc, 32, 64);
  cacc += __shfl_xor(cacc, 16, 64);
  cacc += __shfl_xor(cacc, 8, 64);
  cacc += __shfl_xor(cacc, 4, 64);
  cacc += dpp_qx2(cacc);
  cacc += dpp_qx1(cacc);
  if (l == 0) c_out[b] = cacc;
}

extern "C" void kernel_launch(void* const* d_in, const int* in_sizes, int n_in,
                              void* d_out, int out_size, void* d_ws, size_t ws_size,
                              hipStream_t stream) {
  const float* xinit = (const float*)d_in[0];
  // d_in[1] = current_x (unused by reference), d_in[7] = time (unused)
  const float* cu = (const float*)d_in[2];
  const float* Q  = (const float*)d_in[3];
  const float* p  = (const float*)d_in[4];
  const float* A  = (const float*)d_in[5];
  const float* Bm = (const float*)d_in[6];
  float* out = (float*)d_out;

  lqr_fused<<<dim3(NBQ), dim3(64), 0, stream>>>(Q, p, A, Bm, cu, xinit, out);
}

// Round 6
// 339.383 us; speedup vs baseline: 1.2196x; 1.0385x over previous
//
#include <hip/hip_runtime.h>

// NLQR: NB=1024, T=128, NS=12, NC=4, N=16.
// Round 11 = Round 10 (175.5us) + two bit-exact latency fixes:
//  1) FORWARD: prefetch deepened 3 -> 8 slots. Fw re-reads hit L3 (FETCH =
//     one compulsory pass), L3 latency ~400-600cy > old 3-iter slack (~450cy)
//     -> every fw iter stalled on vmcnt. 8 slots = ~1200cy slack. VGPR is
//     free (occupancy grid-bound at 1 wave/SIMD).
//  2) BACKWARD: DS in-order pipe — issue the 7 critical reads (f, V rows, vv)
//     FIRST, then global-load issue (addr VALU fills read latency), then FTN
//     staging writes (previously 3 writes sat ahead of the reads in the pipe).
// Math untouched — absmax must stay exactly 0.015625 (canary).
// R10 design retained: readlane Quu/qu (Schur entry ~4cy after MKS), stg4
// publish overlapping Schur, single-BB bodies, uniform FT staging, coalesced
// us/xs flush, 4-deep bw prefetch, zero barriers, 1 wave/block.

#define NBQ 1024
#define TT  128

// publish-slot swizzle: distinct bank quads for broadcast reads
#define SSLOT(x) ((x) ^ ((((x) >> 4) << 1)))

__device__ __forceinline__ float dotf4(float4 a, float4 b) {
  return a.x*b.x + a.y*b.y + a.z*b.z + a.w*b.w;
}
__device__ __forceinline__ float dpp_qx1(float x) {  // quad_perm [1,0,3,2]
  return __int_as_float(__builtin_amdgcn_mov_dpp(__float_as_int(x), 0xB1, 0xF, 0xF, true));
}
__device__ __forceinline__ float dpp_qx2(float x) {  // quad_perm [2,3,0,1]
  return __int_as_float(__builtin_amdgcn_mov_dpp(__float_as_int(x), 0x4E, 0xF, 0xF, true));
}
template<int Q> __device__ __forceinline__ float4 bcast4(float4 v) {
  // broadcast quad-lane Q's float4 to all lanes of the quad (pure VALU)
  float4 r;
  r.x = __int_as_float(__builtin_amdgcn_mov_dpp(__float_as_int(v.x), Q*0x55, 0xF, 0xF, true));
  r.y = __int_as_float(__builtin_amdgcn_mov_dpp(__float_as_int(v.y), Q*0x55, 0xF, 0xF, true));
  r.z = __int_as_float(__builtin_amdgcn_mov_dpp(__float_as_int(v.z), Q*0x55, 0xF, 0xF, true));
  r.w = __int_as_float(__builtin_amdgcn_mov_dpp(__float_as_int(v.w), Q*0x55, 0xF, 0xF, true));
  return r;
}
__device__ __forceinline__ float rdlane(float v, int lane) { // uniform broadcast (VALU, no DS)
  return __int_as_float(__builtin_amdgcn_readlane(__float_as_int(v), lane));
}

#define MKS(K, O, MY)  { float4 mk_ = bcast4<O>(MY);                           \
  qt4_.x += gk_[K]*mk_.x; qt4_.y += gk_[K]*mk_.y;                              \
  qt4_.z += gk_[K]*mk_.z; qt4_.w += gk_[K]*mk_.w; }

// One backward body at time T_. Slot regs QV/PV/CV + F-scalars loaded 4 bodies
// ago; stages F^T for T_-1 from prev slot's F-scalars; reloads self slot with
// T_-4 data. FTC/FTN = compile-time parity buffers. ZERO exec-mask regions.
// DS order: critical reads first, then VMEM issue, then staging writes.
#define BW_BODY(T_, QV, PV, CV, P0,P1,P2, S0,S1,S2, FTC, FTN)                  \
{                                                                              \
  const int  t_   = (T_);                                                      \
  const long btL_ = b*TT + ((t_ >= 4) ? (t_ - 4) : 0);                         \
  /* critical DS reads issue first (in-order pipe) */                          \
  const float4* fj4_ = (const float4*)(FTC + j*12);                            \
  float4 f0_=fj4_[0], f1_=fj4_[1], f2_=fj4_[2];                                \
  float4 mv0_ = vns4[kR], mv1_ = vns4[16+kR], mv2_ = vns4[32+kR];              \
  float4 mw_ = *(const float4*)(vvF + 4*dmin);                                 \
  /* global prefetch issue: addr VALU fills the DS read latency */             \
  float4 qN_ = *(const float4*)(Qg + btL_*256 + qoff);                         \
  const float* fpL_ = fBase + btL_*fMul + fOfs;                                \
  float fN0_ = fpL_[0], fN1_ = fpL_[fstr_], fN2_ = fpL_[2*fstr_];              \
  float  pN_ = pg[btL_*16 + j];                                                \
  float  cN_ = cug[btL_*4 + q4];                                               \
  /* stage F^T for t_-1 (writes AFTER the reads in pipe order) */              \
  FTN[wix] = P0; FTN[wix+1] = P1; FTN[wix+2] = P2;                             \
  /* m rows via quad broadcast of V rows (single-use -> DPP folds into fma) */ \
  float m0_, m1_, m2_;                                                         \
  { float4 r0_=bcast4<0>(mv0_), r1_=bcast4<0>(mv1_), r2_=bcast4<0>(mv2_);      \
    m0_ = dotf4(r0_,f0_)+dotf4(r1_,f1_)+dotf4(r2_,f2_); }                      \
  { float4 r0_=bcast4<1>(mv0_), r1_=bcast4<1>(mv1_), r2_=bcast4<1>(mv2_);      \
    m1_ = dotf4(r0_,f0_)+dotf4(r1_,f1_)+dotf4(r2_,f2_); }                      \
  { float4 r0_=bcast4<2>(mv0_), r1_=bcast4<2>(mv1_), r2_=bcast4<2>(mv2_);      \
    m2_ = dotf4(r0_,f0_)+dotf4(r1_,f1_)+dotf4(r2_,f2_); }                      \
  msh[(3*r+0)*16 + j] = m0_;                                                   \
  msh[(3*r+1)*16 + j] = m1_;                                                   \
  msh[(3*r+2)*16 + j] = m2_;                                                   \
  /* qtv via vv quad broadcast (fills msh write->read latency) */              \
  float qtv_;                                                                  \
  { float4 w0_=bcast4<0>(mw_), w1_=bcast4<1>(mw_), w2_=bcast4<2>(mw_);         \
    qtv_ = PV + dotf4(w0_,f0_)+dotf4(w1_,f1_)+dotf4(w2_,f2_); }                \
  /* qt tile: lane (cb, i=l&15) computes Qt[i][4cb..4cb+3] */                  \
  float gk_[12] = {f0_.x,f0_.y,f0_.z,f0_.w, f1_.x,f1_.y,f1_.z,f1_.w,           \
                   f2_.x,f2_.y,f2_.z,f2_.w};                                   \
  float4 mys0_ = *(const float4*)(msh + (3*q4+0)*16 + cb4);                    \
  float4 mys1_ = *(const float4*)(msh + (3*q4+1)*16 + cb4);                    \
  float4 mys2_ = *(const float4*)(msh + (3*q4+2)*16 + cb4);                    \
  float4 qt4_ = QV;                                                            \
  MKS(0,0,mys0_) MKS(1,0,mys1_) MKS(2,0,mys2_)                                 \
  MKS(3,1,mys0_) MKS(4,1,mys1_) MKS(5,1,mys2_)                                 \
  MKS(6,2,mys0_) MKS(7,2,mys1_) MKS(8,2,mys2_)                                 \
  MKS(9,3,mys0_) MKS(10,3,mys1_) MKS(11,3,mys2_)                               \
  /* publish qt4_ (needed for ux/xr gather); DS write overlaps Schur below */  \
  stg4[sw_] = qt4_;                                                            \
  /* ux/xr reads issue on DS pipe; results consumed only after inv_ ready */   \
  float4 ux0_ = stg4[sux0], ux1_ = stg4[sux1], ux2_ = stg4[sux2], ux3_ = stg4[sux3]; \
  float4 xr_  = stg4[sxr];                                                     \
  /* Quu + qu via readlane (VALU, no DS): Schur entry ~4cy after MKS */        \
  float mm_[16] = {                                                            \
    rdlane(qt4_.x,60), rdlane(qt4_.y,60), rdlane(qt4_.z,60), rdlane(qt4_.w,60),\
    rdlane(qt4_.x,61), rdlane(qt4_.y,61), rdlane(qt4_.z,61), rdlane(qt4_.w,61),\
    rdlane(qt4_.x,62), rdlane(qt4_.y,62), rdlane(qt4_.z,62), rdlane(qt4_.w,62),\
    rdlane(qt4_.x,63), rdlane(qt4_.y,63), rdlane(qt4_.z,63), rdlane(qt4_.w,63)};\
  float4 quv_;                                                                 \
  quv_.x=rdlane(qtv_,12); quv_.y=rdlane(qtv_,13);                              \
  quv_.z=rdlane(qtv_,14); quv_.w=rdlane(qtv_,15);                              \
  /* SPD 2x2-block Schur inverse of Quu (raw v_rcp) */                         \
  float rdp_ = __builtin_amdgcn_rcpf(mm_[0]*mm_[5] - mm_[1]*mm_[1]);           \
  float pi00_ = mm_[5]*rdp_, pi01_ = -mm_[1]*rdp_, pi11_ = mm_[0]*rdp_;        \
  float w00_ = pi00_*mm_[2] + pi01_*mm_[6];                                    \
  float w01_ = pi00_*mm_[3] + pi01_*mm_[7];                                    \
  float w10_ = pi01_*mm_[2] + pi11_*mm_[6];                                    \
  float w11_ = pi01_*mm_[3] + pi11_*mm_[7];                                    \
  float t00_ = mm_[10] - (mm_[2]*w00_ + mm_[6]*w10_);                          \
  float t01_ = mm_[11] - (mm_[2]*w01_ + mm_[6]*w11_);                          \
  float t11_ = mm_[15] - (mm_[3]*w01_ + mm_[7]*w11_);                          \
  float rdt_ = __builtin_amdgcn_rcpf(t00_*t11_ - t01_*t01_);                   \
  float ti00_ = t11_*rdt_, ti01_ = -t01_*rdt_, ti11_ = t00_*rdt_;              \
  float u00_ = -(w00_*ti00_ + w01_*ti01_);                                     \
  float u01_ = -(w00_*ti01_ + w01_*ti11_);                                     \
  float u10_ = -(w10_*ti00_ + w11_*ti01_);                                     \
  float u11_ = -(w10_*ti01_ + w11_*ti11_);                                     \
  float i00_ = pi00_ - (u00_*w00_ + u01_*w01_);                                \
  float i01_ = pi01_ - (u00_*w10_ + u01_*w11_);                                \
  float i11_ = pi11_ - (u10_*w10_ + u11_*w11_);                                \
  float inv_[16] = { i00_, i01_, u00_, u01_,                                   \
                     i01_, i11_, u10_, u11_,                                   \
                     u00_, u10_, ti00_, ti01_,                                 \
                     u01_, u11_, ti01_, ti11_ };                               \
  float kt0_ = -(inv_[0] *quv_.x + inv_[1] *quv_.y + inv_[2] *quv_.z + inv_[3] *quv_.w); \
  float kt1_ = -(inv_[4] *quv_.x + inv_[5] *quv_.y + inv_[6] *quv_.z + inv_[7] *quv_.w); \
  float kt2_ = -(inv_[8] *quv_.x + inv_[9] *quv_.y + inv_[10]*quv_.z + inv_[11]*quv_.w); \
  float kt3_ = -(inv_[12]*quv_.x + inv_[13]*quv_.y + inv_[14]*quv_.z + inv_[15]*quv_.w); \
  float4 kc_[4];                                                               \
  _Pragma("unroll")                                                            \
  for (int c_ = 0; c_ < 4; ++c_) {                                             \
    kc_[c_].x = -(inv_[c_*4+0]*ux0_.x + inv_[c_*4+1]*ux1_.x + inv_[c_*4+2]*ux2_.x + inv_[c_*4+3]*ux3_.x); \
    kc_[c_].y = -(inv_[c_*4+0]*ux0_.y + inv_[c_*4+1]*ux1_.y + inv_[c_*4+2]*ux2_.y + inv_[c_*4+3]*ux3_.y); \
    kc_[c_].z = -(inv_[c_*4+0]*ux0_.z + inv_[c_*4+1]*ux1_.z + inv_[c_*4+2]*ux2_.z + inv_[c_*4+3]*ux3_.z); \
    kc_[c_].w = -(inv_[c_*4+0]*ux0_.w + inv_[c_*4+1]*ux1_.w + inv_[c_*4+2]*ux2_.w + inv_[c_*4+3]*ux3_.w); \
  }                                                                            \
  /* all-lane vn publish (garbage slots never read) */                         \
  float4 vn4_;                                                                 \
  vn4_.x = qt4_.x + xr_.x*kc_[0].x + xr_.y*kc_[1].x + xr_.z*kc_[2].x + xr_.w*kc_[3].x; \
  vn4_.y = qt4_.y + xr_.x*kc_[0].y + xr_.y*kc_[1].y + xr_.z*kc_[2].y + xr_.w*kc_[3].y; \
  vn4_.z = qt4_.z + xr_.x*kc_[0].z + xr_.y*kc_[1].z + xr_.z*kc_[2].z + xr_.w*kc_[3].z; \
  vn4_.w = qt4_.w + xr_.x*kc_[0].w + xr_.y*kc_[1].w + xr_.z*kc_[2].w + xr_.w*kc_[3].w; \
  vns4[l] = vn4_;                                                              \
  vvF[l] = qtv_ + xr_.x*kt0_ + xr_.y*kt1_ + xr_.z*kt2_ + xr_.w*kt3_;           \
  float uv_ = CV + ((q4==0)?kt0_:(q4==1)?kt1_:(q4==2)?kt2_:kt3_);              \
  upt[0] = uv_; upt -= ustp;                                                   \
  QV = qN_; S0 = fN0_; S1 = fN1_; S2 = fN2_; PV = pN_; CV = cN_;               \
}

// forward: load slot for time TI
#define FW_LOAD(QF, FF, PF, TI) {                                              \
  const long bt__ = base + (TI);                                               \
  QF = *(const float4*)(Qg + bt__*256 + 4*l);                                  \
  FF = (q4 < 3) ? *(const float4*)(Ag + bt__*144 + i4c*12 + c0f)               \
                : *(const float4*)(Bg + bt__*48  + i4c*4);                     \
  PF = pg[bt__*16 + i4]; }

// forward body at time T_: consume slot, then re-issue it for T_+8 (clamped)
#define FW_BODY(T_, QF, FF, PF) {                                              \
  const int t__ = (T_);                                                        \
  float4 u4 = *(const float4*)(uL + t__*4);                                    \
  float4 xg;                                                                   \
  xg.x = __shfl(s, sl0, 64); xg.y = __shfl(s, sl1, 64);                        \
  xg.z = __shfl(s, sl2, 64); xg.w = __shfl(s, sl3, 64);                        \
  float4 xuq = (q4 < 3) ? xg : u4;                                             \
  float xui = (i4 < 12) ? s                                                    \
            : (i4 == 12) ? u4.x : (i4 == 13) ? u4.y : (i4 == 14) ? u4.z : u4.w;\
  xpt[0] = s; xpt += xstp;                                                     \
  cacc += 0.5f * xui * dotf4(QF, xuq);                                         \
  cacc += q0m * (xui * PF);                                                    \
  float zx = dotf4(FF, xuq);                                                   \
  zx += dpp_qx1(zx);                                                           \
  zx += dpp_qx2(zx);                                                           \
  s = zx;                                                                      \
  const int tn__ = (t__ + 8 <= TT-1) ? (t__ + 8) : (TT-1);                     \
  FW_LOAD(QF, FF, PF, tn__)                                                    \
}

__global__ __launch_bounds__(64, 1) void lqr_fused(
    const float* __restrict__ Qg, const float* __restrict__ pg,
    const float* __restrict__ Ag, const float* __restrict__ Bg,
    const float* __restrict__ cug, const float* __restrict__ xinit,
    float* __restrict__ out)
{
  __shared__ __align__(16) float lds[3264];
  float*  FT0  = lds;                    // [16][12] F^T buffer 0
  float*  FT1  = lds + 192;              // [16][12] F^T buffer 1
  float*  msh  = lds + 384;              // [12][16]
  float4* stg4 = (float4*)(lds + 576);   // [64] qt4_ publish (swizzled slots)
  float4* vns4 = (float4*)(lds + 832);   // [64] vn4_ publish
  float*  vvF  = lds + 1088;             // [64] vv publish
  float*  uL   = lds + 1152;             // [128][4]
  float*  dmpS = lds + 1664;             // [64] dump row (never read)
  float*  xsL  = lds + 1728;             // [128][12]

  const int l    = threadIdx.x;
  const int j    = l & 15;         // m-step col / qt-step row i
  const int r    = l >> 4;         // m-step row group
  const int q4   = l & 3;
  const int cb   = l >> 4;         // qt-step column block
  const int cb4  = cb << 2;
  const int dmin = (q4 < 2) ? q4 : 2;
  const int jc   = (j < 12) ? j : 11;
  const long b   = blockIdx.x;
  const int  kR  = 3*r + dmin;

  // publish-slot indices (hoisted)
  const int sw_  = SSLOT(l);
  const int sux0 = SSLOT(16*cb + 12), sux1 = SSLOT(16*cb + 13);
  const int sux2 = SSLOT(16*cb + 14), sux3 = SSLOT(16*cb + 15);
  const int sxr  = SSLOT(48 + jc);

  // uniform F^T staging map: lane l stages FT[n][k0..k0+2]
  const int  n_   = l >> 2;
  const int  k0_  = 3*(l & 3);
  const int  wix  = n_*12 + k0_;
  const bool isA  = (n_ < 12);
  const float* fBase = isA ? Ag : Bg;
  const int  fMul  = isA ? 144 : 48;
  const int  fstr_ = isA ? 12  : 4;
  const int  fOfs  = isA ? (k0_*12 + n_) : (k0_*4 + (n_ - 12));
  const int  qoff  = j * 16 + cb4;

  // u store: lanes 0..3 write uL[t*4+l], others to dump (b32, conflict-free)
  float* up0 = (l < 4) ? (uL + l) : (dmpS + l);
  const int ustp = (l < 4) ? 4 : 0;
  float* upt = up0 + 127*ustp;   // walks t = 127..0 via upt -= ustp

  float* xs_out = out;
  float* us_out = out + (long)NBQ*TT*12;
  float* c_out  = out + (long)NBQ*TT*12 + (long)NBQ*TT*4;

  vns4[l] = make_float4(0.f,0.f,0.f,0.f);
  vvF[l]  = 0.f;

  // ---- prologue: 4 slots (t = 127..124), stage FT(127) into buf1 ----
  const long base = b*TT;
  float4 q3v,q2v,q1v,q0v;
  float  p3v,c3v,p2v,c2v,p1v,c1v,p0v,c0v;
  float  f3a,f3b,f3c, f2a,f2b,f2c, f1a,f1b,f1c, f0a,f0b,f0c;
  {
    long bt;
    bt = base+127; q3v=*(const float4*)(Qg+bt*256+qoff); p3v=pg[bt*16+j]; c3v=cug[bt*4+q4];
    { const float* fp = fBase + bt*fMul + fOfs; f3a=fp[0]; f3b=fp[fstr_]; f3c=fp[2*fstr_]; }
    bt = base+126; q2v=*(const float4*)(Qg+bt*256+qoff); p2v=pg[bt*16+j]; c2v=cug[bt*4+q4];
    { const float* fp = fBase + bt*fMul + fOfs; f2a=fp[0]; f2b=fp[fstr_]; f2c=fp[2*fstr_]; }
    bt = base+125; q1v=*(const float4*)(Qg+bt*256+qoff); p1v=pg[bt*16+j]; c1v=cug[bt*4+q4];
    { const float* fp = fBase + bt*fMul + fOfs; f1a=fp[0]; f1b=fp[fstr_]; f1c=fp[2*fstr_]; }
    bt = base+124; q0v=*(const float4*)(Qg+bt*256+qoff); p0v=pg[bt*16+j]; c0v=cug[bt*4+q4];
    { const float* fp = fBase + bt*fMul + fOfs; f0a=fp[0]; f0b=fp[fstr_]; f0c=fp[2*fstr_]; }
  }
  FT1[wix] = f3a; FT1[wix+1] = f3b; FT1[wix+2] = f3c;

  // ---- backward scan, unrolled x4 with slot rotation ----
  #pragma unroll 1
  for (int tb = TT-1; tb >= 3; tb -= 4) {
    BW_BODY(tb,   q3v, p3v, c3v,  f2a,f2b,f2c,  f3a,f3b,f3c, FT1, FT0)
    BW_BODY(tb-1, q2v, p2v, c2v,  f1a,f1b,f1c,  f2a,f2b,f2c, FT0, FT1)
    BW_BODY(tb-2, q1v, p1v, c1v,  f0a,f0b,f0c,  f1a,f1b,f1c, FT1, FT0)
    BW_BODY(tb-3, q0v, p0v, c0v,  f3a,f3b,f3c,  f0a,f0b,f0c, FT0, FT1)
  }

  // ---- coalesced us flush (replaces per-body predicated global store) ----
  #pragma unroll
  for (int i_ = 0; i_ < 8; ++i_) us_out[b*512 + i_*64 + l] = uL[i_*64 + l];

  // ---------------- forward rollout + cost ----------------
  const int i4  = l >> 2;
  const int c0f = q4 << 2;
  const int i4c = (i4 < 12) ? i4 : 11;
  const int sl0 = (c0f+0)<<2, sl1 = (c0f+1)<<2, sl2 = (c0f+2)<<2, sl3 = (c0f+3)<<2;
  float s = xinit[b*12 + i4c];
  float cacc = 0.f;

  // de-predicated x store + cost mask
  const bool xc_ = (q4 == 0) && (i4 < 12);
  float* xpt = xc_ ? (xsL + i4) : (dmpS + l);
  const int xstp = xc_ ? 12 : 0;
  const float q0m = (q4 == 0) ? 1.0f : 0.0f;

  // 8-deep prefetch slots
  float4 qf0,qf1,qf2,qf3,qf4,qf5,qf6,qf7;
  float4 ff0,ff1,ff2,ff3,ff4,ff5,ff6,ff7;
  float  pf0,pf1,pf2,pf3,pf4,pf5,pf6,pf7;
  FW_LOAD(qf0,ff0,pf0, 0) FW_LOAD(qf1,ff1,pf1, 1)
  FW_LOAD(qf2,ff2,pf2, 2) FW_LOAD(qf3,ff3,pf3, 3)
  FW_LOAD(qf4,ff4,pf4, 4) FW_LOAD(qf5,ff5,pf5, 5)
  FW_LOAD(qf6,ff6,pf6, 6) FW_LOAD(qf7,ff7,pf7, 7)

  #pragma unroll 1
  for (int tg = 0; tg < TT; tg += 8) {
    FW_BODY(tg+0, qf0, ff0, pf0)
    FW_BODY(tg+1, qf1, ff1, pf1)
    FW_BODY(tg+2, qf2, ff2, pf2)
    FW_BODY(tg+3, qf3, ff3, pf3)
    FW_BODY(tg+4, qf4, ff4, pf4)
    FW_BODY(tg+5, qf5, ff5, pf5)
    FW_BODY(tg+6, qf6, ff6, pf6)
    FW_BODY(tg+7, qf7, ff7, pf7)
  }

  // ---- coalesced xs flush ----
  #pragma unroll
  for (int i_ = 0; i_ < 24; ++i_) xs_out[b*1536 + i_*64 + l] = xsL[i_*64 + l];

  cacc += __shfl_xor(cacc, 32, 64);
  cacc += __shfl_xor(cacc, 16, 64);
  cacc += __shfl_xor(cacc, 8, 64);
  cacc += __shfl_xor(cacc, 4, 64);
  cacc += dpp_qx2(cacc);
  cacc += dpp_qx1(cacc);
  if (l == 0) c_out[b] = cacc;
}

extern "C" void kernel_launch(void* const* d_in, const int* in_sizes, int n_in,
                              void* d_out, int out_size, void* d_ws, size_t ws_size,
                              hipStream_t stream) {
  const float* xinit = (const float*)d_in[0];
  // d_in[1] = current_x (unused by reference), d_in[7] = time (unused)
  const float* cu = (const float*)d_in[2];
  const float* Q  = (const float*)d_in[3];
  const float* p  = (const float*)d_in[4];
  const float* A  = (const float*)d_in[5];
  const float* Bm = (const float*)d_in[6];
  float* out = (float*)d_out;

  lqr_fused<<<dim3(NBQ), dim3(64), 0, stream>>>(Q, p, A, Bm, cu, xinit, out);
}